// Round 1
// baseline (1540.200 us; speedup 1.0000x reference)
//
#include <hip/hip_runtime.h>
#include <hip/hip_bf16.h>
#include <math.h>

#define NSEQ 1048576           // S*DIM = 1024*1024 elements per [1024,1024] matrix
#define SCALE_QK (1.0f/32.0f)  // 1/sqrt(1024)

// ---------------- block reductions ----------------
__device__ __forceinline__ float block_reduce_max(float v, float* red) {
    int t = threadIdx.x;
    red[t] = v; __syncthreads();
    #pragma unroll
    for (int off = 128; off; off >>= 1) {
        if (t < off) red[t] = fmaxf(red[t], red[t + off]);
        __syncthreads();
    }
    float r = red[0]; __syncthreads();
    return r;
}
__device__ __forceinline__ float block_reduce_sum(float v, float* red) {
    int t = threadIdx.x;
    red[t] = v; __syncthreads();
    #pragma unroll
    for (int off = 128; off; off >>= 1) {
        if (t < off) red[t] += red[t + off];
        __syncthreads();
    }
    float r = red[0]; __syncthreads();
    return r;
}

// ---------------- router ----------------
// logits[b,e] = X[b].flat . switch_W[:,e]   (1M-long dot products)
__global__ __launch_bounds__(256) void router_partial(const float* __restrict__ X,
                                                      const float* __restrict__ sW,
                                                      float* __restrict__ part) {
    float acc[32];
    #pragma unroll
    for (int a = 0; a < 32; ++a) acc[a] = 0.f;
    int tid = blockIdx.x * 256 + threadIdx.x;
    for (int i = tid; i < NSEQ; i += 65536) {
        float4 w0 = *(const float4*)(sW + (size_t)i * 8);
        float4 w1 = *(const float4*)(sW + (size_t)i * 8 + 4);
        #pragma unroll
        for (int b = 0; b < 4; ++b) {
            float x = X[(size_t)b * NSEQ + i];
            acc[b*8+0] += x * w0.x; acc[b*8+1] += x * w0.y;
            acc[b*8+2] += x * w0.z; acc[b*8+3] += x * w0.w;
            acc[b*8+4] += x * w1.x; acc[b*8+5] += x * w1.y;
            acc[b*8+6] += x * w1.z; acc[b*8+7] += x * w1.w;
        }
    }
    __shared__ float red[256];
    int t = threadIdx.x;
    for (int a = 0; a < 32; ++a) {
        red[t] = acc[a]; __syncthreads();
        for (int off = 128; off; off >>= 1) {
            if (t < off) red[t] += red[t + off];
            __syncthreads();
        }
        if (t == 0) part[blockIdx.x * 32 + a] = red[0];
        __syncthreads();
    }
}

// reduce partials, add bias, pick top-2 per batch (ties -> lowest index, like lax.top_k)
__global__ __launch_bounds__(256) void router_final(const float* __restrict__ part,
                                                    const float* __restrict__ sb,
                                                    float* __restrict__ logits,
                                                    int* __restrict__ sel) {
    __shared__ float lg[32];
    int t = threadIdx.x;
    if (t < 32) {
        float s = 0.f;
        for (int blk = 0; blk < 256; ++blk) s += part[blk * 32 + t];
        s += sb[t & 7];
        lg[t] = s;
        logits[t] = s;
    }
    __syncthreads();
    if (t < 4) {
        int base = t * 8;
        int e1 = 0; float v1 = lg[base];
        for (int e = 1; e < 8; ++e) { if (lg[base + e] > v1) { v1 = lg[base + e]; e1 = e; } }
        int e2 = -1; float v2 = -INFINITY;
        for (int e = 0; e < 8; ++e) {
            if (e == e1) continue;
            if (lg[base + e] > v2) { v2 = lg[base + e]; e2 = e; }
        }
        sel[t * 2] = e1; sel[t * 2 + 1] = e2;
    }
}

// ---------------- fp32 tiled GEMM core: C(64x64 tile) = A[1024xK=1024] @ B ----------------
// TB=false: B is [1024 x 1024] row-major (k rows).  TB=true: B is [1024 x 1024] with output
// col n indexing B's ROW (i.e. C = A @ B^T).
template<bool TB>
__device__ __forceinline__ void gemm_tile_1024(const float* __restrict__ A,
                                               const float* __restrict__ B,
                                               float (&c)[4][4]) {
    __shared__ float sA[32][68];   // [k][m], padded stride 68 (272B = 17*16B, float4-aligned)
    __shared__ float sB[32][68];   // [k][n]
    const int t  = threadIdx.x;
    const int tx = t & 15, ty = t >> 4;
    const int m0 = blockIdx.y * 64, n0 = blockIdx.x * 64;

    #pragma unroll
    for (int i = 0; i < 4; ++i)
        #pragma unroll
        for (int j = 0; j < 4; ++j) c[i][j] = 0.f;

    for (int k0 = 0; k0 < 1024; k0 += 32) {
        // A tile 64x32 -> sA[k][m] (transposed store)
        #pragma unroll
        for (int cc = 0; cc < 2; ++cc) {
            int chunk = t + cc * 256;
            int row = chunk >> 3;            // m (0..63)
            int kf  = (chunk & 7) << 2;      // k float4 offset
            float4 v = *(const float4*)(A + (size_t)(m0 + row) * 1024 + k0 + kf);
            sA[kf+0][row] = v.x; sA[kf+1][row] = v.y;
            sA[kf+2][row] = v.z; sA[kf+3][row] = v.w;
        }
        if (!TB) {
            // B tile 32x64 -> sB[k][n] direct
            #pragma unroll
            for (int cc = 0; cc < 2; ++cc) {
                int chunk = t + cc * 256;
                int row = chunk >> 4;        // k (0..31)
                int nf  = (chunk & 15) << 2; // n float4 offset
                float4 v = *(const float4*)(B + (size_t)(k0 + row) * 1024 + n0 + nf);
                *(float4*)&sB[row][nf] = v;
            }
        } else {
            // B^T: B rows are n, cols are k -> transpose into sB[k][n]
            #pragma unroll
            for (int cc = 0; cc < 2; ++cc) {
                int chunk = t + cc * 256;
                int row = chunk >> 3;        // n (0..63)
                int kf  = (chunk & 7) << 2;
                float4 v = *(const float4*)(B + (size_t)(n0 + row) * 1024 + k0 + kf);
                sB[kf+0][row] = v.x; sB[kf+1][row] = v.y;
                sB[kf+2][row] = v.z; sB[kf+3][row] = v.w;
            }
        }
        __syncthreads();
        #pragma unroll
        for (int kk = 0; kk < 32; ++kk) {
            float4 a4 = *(const float4*)&sA[kk][ty << 2];
            float4 b4 = *(const float4*)&sB[kk][tx << 2];
            float a[4] = {a4.x, a4.y, a4.z, a4.w};
            float bb[4] = {b4.x, b4.y, b4.z, b4.w};
            #pragma unroll
            for (int i = 0; i < 4; ++i)
                #pragma unroll
                for (int j = 0; j < 4; ++j) c[i][j] += a[i] * bb[j];
        }
        __syncthreads();
    }
}

__device__ __forceinline__ void store_tile(float* __restrict__ C, const float (&c)[4][4],
                                           float scale, const float* __restrict__ bias) {
    const int t  = threadIdx.x;
    const int tx = t & 15, ty = t >> 4;
    const int m0 = blockIdx.y * 64, n0 = blockIdx.x * 64;
    #pragma unroll
    for (int i = 0; i < 4; ++i) {
        int m = m0 + (ty << 2) + i;
        int n = n0 + (tx << 2);
        float4 v;
        v.x = c[i][0] * scale; v.y = c[i][1] * scale;
        v.z = c[i][2] * scale; v.w = c[i][3] * scale;
        if (bias) { v.x += bias[n]; v.y += bias[n+1]; v.z += bias[n+2]; v.w += bias[n+3]; }
        *(float4*)(C + (size_t)m * 1024 + n) = v;
    }
}

// ---------------- GEMM wrapper kernels ----------------
// z = slot*? : proj z in [0,6): slot = z&1, w = z>>1 (0=Q,1=K,2=V)
__global__ __launch_bounds__(256) void proj_kernel(const float* __restrict__ X,
        const float* __restrict__ Wq, const float* __restrict__ bq,
        const float* __restrict__ Wk, const float* __restrict__ bk,
        const float* __restrict__ Wv, const float* __restrict__ bv,
        const int* __restrict__ sel, int b, float* __restrict__ qkv) {
    int z = blockIdx.z;
    int slot = z & 1, w = z >> 1;
    int e = sel[b * 2 + slot];
    const float* W    = (w == 0 ? Wq : (w == 1 ? Wk : Wv)) + (size_t)e * NSEQ;
    const float* bias = (w == 0 ? bq : (w == 1 ? bk : bv)) + e * 1024;
    const float* A = X + (size_t)b * NSEQ;
    float* C = qkv + (size_t)(w * 2 + slot) * NSEQ;
    float c[4][4];
    gemm_tile_1024<false>(A, W, c);
    store_tile(C, c, 1.0f, bias);
}

__global__ __launch_bounds__(256) void scores_kernel(const float* __restrict__ qkv,
                                                     float* __restrict__ Sb) {
    int slot = blockIdx.z;
    const float* Q = qkv + (size_t)slot * NSEQ;
    const float* K = qkv + (size_t)(2 + slot) * NSEQ;
    float c[4][4];
    gemm_tile_1024<true>(Q, K, c);
    store_tile(Sb + (size_t)slot * NSEQ, c, SCALE_QK, nullptr);
}

// A[s,:] = softmax(S0[s,:]) + softmax(S1[s,:])
__global__ __launch_bounds__(256) void softmax_combine(const float* __restrict__ S0,
                                                       const float* __restrict__ S1,
                                                       float* __restrict__ Ab) {
    __shared__ float red[256];
    int s = blockIdx.x, t = threadIdx.x;
    float4 x0 = *(const float4*)(S0 + (size_t)s * 1024 + t * 4);
    float4 x1 = *(const float4*)(S1 + (size_t)s * 1024 + t * 4);
    float m0 = fmaxf(fmaxf(x0.x, x0.y), fmaxf(x0.z, x0.w));
    float m1 = fmaxf(fmaxf(x1.x, x1.y), fmaxf(x1.z, x1.w));
    m0 = block_reduce_max(m0, red);
    m1 = block_reduce_max(m1, red);
    float4 e0, e1;
    e0.x = __expf(x0.x - m0); e0.y = __expf(x0.y - m0);
    e0.z = __expf(x0.z - m0); e0.w = __expf(x0.w - m0);
    e1.x = __expf(x1.x - m1); e1.y = __expf(x1.y - m1);
    e1.z = __expf(x1.z - m1); e1.w = __expf(x1.w - m1);
    float s0 = block_reduce_sum(e0.x + e0.y + e0.z + e0.w, red);
    float s1 = block_reduce_sum(e1.x + e1.y + e1.z + e1.w, red);
    float r0 = 1.f / s0, r1 = 1.f / s1;
    float4 o;
    o.x = e0.x * r0 + e1.x * r1; o.y = e0.y * r0 + e1.y * r1;
    o.z = e0.z * r0 + e1.z * r1; o.w = e0.w * r0 + e1.w * r1;
    *(float4*)(Ab + (size_t)s * 1024 + t * 4) = o;
}

__global__ __launch_bounds__(256) void ctx_kernel(const float* __restrict__ Ab,
                                                  const float* __restrict__ qkv,
                                                  float* __restrict__ ctx) {
    int slot = blockIdx.z;
    const float* V = qkv + (size_t)(4 + slot) * NSEQ;
    float c[4][4];
    gemm_tile_1024<false>(Ab, V, c);
    store_tile(ctx + (size_t)slot * NSEQ, c, 1.0f, nullptr);
}

__global__ __launch_bounds__(256) void outp_kernel(const float* __restrict__ ctx,
                                                   const float* __restrict__ Wff,
                                                   const int* __restrict__ sel, int b,
                                                   float* __restrict__ O) {
    int slot = blockIdx.z;
    int e = sel[b * 2 + slot];
    float c[4][4];
    gemm_tile_1024<false>(ctx + (size_t)slot * NSEQ, Wff + (size_t)e * NSEQ, c);
    store_tile(O + (size_t)slot * NSEQ, c, 1.0f, nullptr);
}

__global__ __launch_bounds__(256) void combine_kernel(const float* __restrict__ O0,
                                                      const float* __restrict__ O1,
                                                      const float* __restrict__ bff,
                                                      const int* __restrict__ sel, int b,
                                                      float* __restrict__ y) {
    int i = blockIdx.x * 256 + threadIdx.x;   // 0 .. 1M-1
    int d = i & 1023;
    int e0 = sel[b * 2], e1 = sel[b * 2 + 1];
    y[(size_t)b * NSEQ + i] = O0[i] + O1[i] + bff[e0 * 1024 + d] + bff[e1 * 1024 + d];
}

// ---------------- launcher ----------------
extern "C" void kernel_launch(void* const* d_in, const int* in_sizes, int n_in,
                              void* d_out, int out_size, void* d_ws, size_t ws_size,
                              hipStream_t stream) {
    const float* X   = (const float*)d_in[0];
    // d_in[1] = mask (unused by the reference math)
    const float* sW  = (const float*)d_in[2];
    const float* sb  = (const float*)d_in[3];
    const float* Wq  = (const float*)d_in[4];
    const float* bq  = (const float*)d_in[5];
    const float* Wk  = (const float*)d_in[6];
    const float* bk  = (const float*)d_in[7];
    const float* Wv  = (const float*)d_in[8];
    const float* bv  = (const float*)d_in[9];
    const float* Wff = (const float*)d_in[10];
    const float* bff = (const float*)d_in[11];
    float* y = (float*)d_out;

    float* ws     = (float*)d_ws;
    float* part   = ws;                    // 256*32 floats
    float* logits = ws + 8192;             // 32
    int*   sel    = (int*)(ws + 8224);     // 8 ints
    float* big    = ws + 16384;            // 64KB-aligned-ish start of big buffers
    float* qkv    = big;                   // 6 * 1M floats (Q0,Q1,K0,K1,V0,V1)
    float* Sbuf   = qkv + 6 * (size_t)NSEQ;   // 2 * 1M
    float* Ab     = Sbuf + 2 * (size_t)NSEQ;  // 1M
    float* ctx    = Ab + (size_t)NSEQ;        // 2 * 1M
    float* Obuf   = ctx + 2 * (size_t)NSEQ;   // 2 * 1M
    // total ws use ~ 54.6 MB

    router_partial<<<256, 256, 0, stream>>>(X, sW, part);
    router_final<<<1, 256, 0, stream>>>(part, sb, logits, sel);

    dim3 blk(256);
    for (int b = 0; b < 4; ++b) {
        proj_kernel<<<dim3(16, 16, 6), blk, 0, stream>>>(X, Wq, bq, Wk, bk, Wv, bv, sel, b, qkv);
        scores_kernel<<<dim3(16, 16, 2), blk, 0, stream>>>(qkv, Sbuf);
        softmax_combine<<<1024, 256, 0, stream>>>(Sbuf, Sbuf + (size_t)NSEQ, Ab);
        ctx_kernel<<<dim3(16, 16, 2), blk, 0, stream>>>(Ab, qkv, ctx);
        outp_kernel<<<dim3(16, 16, 2), blk, 0, stream>>>(ctx, Wff, sel, b, Obuf);
        combine_kernel<<<4096, blk, 0, stream>>>(Obuf, Obuf + (size_t)NSEQ, bff, sel, b, y);
    }
}

// Round 2
// 292.743 us; speedup vs baseline: 5.2613x; 5.2613x over previous
//
#include <hip/hip_runtime.h>
#include <math.h>

typedef unsigned short u16;
typedef __attribute__((ext_vector_type(8))) short bffrag;   // 8 bf16 MFMA operand
typedef __attribute__((ext_vector_type(4))) float f32x4;    // MFMA accumulator
typedef __attribute__((ext_vector_type(4))) unsigned short us4;
typedef __attribute__((ext_vector_type(8))) unsigned short us8;

#define SCALE_QK (1.0f/32.0f)

// fp32 -> bf16 round-to-nearest-even (bit trick, NaN-free inputs)
__device__ __forceinline__ u16 f2bf(float f) {
    unsigned u = __builtin_bit_cast(unsigned, f);
    u += 0x7fffu + ((u >> 16) & 1u);
    return (u16)(u >> 16);
}

__device__ __forceinline__ void gld16(const u16* g, u16* l) {
    __builtin_amdgcn_global_load_lds(
        (const __attribute__((address_space(1))) void*)g,
        (__attribute__((address_space(3))) void*)l, 16, 0, 0);
}

// ---------------- router (fp32, exact) ----------------
__global__ __launch_bounds__(256) void router_partial(const float* __restrict__ X,
                                                      const float* __restrict__ sW,
                                                      float* __restrict__ part) {
    float acc[32];
    #pragma unroll
    for (int a = 0; a < 32; ++a) acc[a] = 0.f;
    int tid = blockIdx.x * 256 + threadIdx.x;
    for (int i = tid; i < (1 << 20); i += 65536) {
        float4 w0 = *(const float4*)(sW + (size_t)i * 8);
        float4 w1 = *(const float4*)(sW + (size_t)i * 8 + 4);
        #pragma unroll
        for (int b = 0; b < 4; ++b) {
            float x = X[((size_t)b << 20) + i];
            acc[b*8+0] += x * w0.x; acc[b*8+1] += x * w0.y;
            acc[b*8+2] += x * w0.z; acc[b*8+3] += x * w0.w;
            acc[b*8+4] += x * w1.x; acc[b*8+5] += x * w1.y;
            acc[b*8+6] += x * w1.z; acc[b*8+7] += x * w1.w;
        }
    }
    __shared__ float red[256];
    int t = threadIdx.x;
    for (int a = 0; a < 32; ++a) {
        red[t] = acc[a]; __syncthreads();
        for (int off = 128; off; off >>= 1) {
            if (t < off) red[t] += red[t + off];
            __syncthreads();
        }
        if (t == 0) part[blockIdx.x * 32 + a] = red[0];
        __syncthreads();
    }
}

__global__ __launch_bounds__(256) void router_final(const float* __restrict__ part,
                                                    const float* __restrict__ sb,
                                                    int* __restrict__ sel) {
    __shared__ float lg[32];
    int t = threadIdx.x;
    if (t < 32) {
        float s = 0.f;
        for (int blk = 0; blk < 256; ++blk) s += part[blk * 32 + t];
        lg[t] = s + sb[t & 7];
    }
    __syncthreads();
    if (t < 4) {
        int base = t * 8;
        int e1 = 0; float v1 = lg[base];
        for (int e = 1; e < 8; ++e) { if (lg[base + e] > v1) { v1 = lg[base + e]; e1 = e; } }
        int e2 = -1; float v2 = -INFINITY;
        for (int e = 0; e < 8; ++e) {
            if (e == e1) continue;
            if (lg[base + e] > v2) { v2 = lg[base + e]; e2 = e; }
        }
        sel[t * 2] = e1; sel[t * 2 + 1] = e2;
    }
}

// ---------------- converts ----------------
__global__ __launch_bounds__(256) void cvt_x(const float* __restrict__ X, u16* __restrict__ Xb) {
    int i = (blockIdx.x * 256 + threadIdx.x) * 8;
    float4 a = *(const float4*)(X + i);
    float4 b = *(const float4*)(X + i + 4);
    us8 o;
    o[0] = f2bf(a.x); o[1] = f2bf(a.y); o[2] = f2bf(a.z); o[3] = f2bf(a.w);
    o[4] = f2bf(b.x); o[5] = f2bf(b.y); o[6] = f2bf(b.z); o[7] = f2bf(b.w);
    *(us8*)(Xb + i) = o;
}

// transpose + convert one 1024x1024 fp32 matrix -> bf16 transposed
__global__ __launch_bounds__(256) void cvt_w_t(const float* __restrict__ Wq,
                                               const float* __restrict__ Wk,
                                               const float* __restrict__ Wv,
                                               const float* __restrict__ Wff,
                                               u16* __restrict__ WqT, u16* __restrict__ WkT,
                                               u16* __restrict__ WvT, u16* __restrict__ WffT) {
    __shared__ float tbuf[64][65];
    int z = blockIdx.z;                  // 0..31
    int which = z >> 3, e = z & 7;
    const float* src = (which == 0 ? Wq : which == 1 ? Wk : which == 2 ? Wv : Wff) + ((size_t)e << 20);
    u16* dst = (which == 0 ? WqT : which == 1 ? WkT : which == 2 ? WvT : WffT) + ((size_t)e << 20);
    int r0 = blockIdx.y * 64, c0 = blockIdx.x * 64;
    int tid = threadIdx.x;
    #pragma unroll
    for (int q = 0; q < 4; ++q) {
        int ch = q * 256 + tid;          // 0..1023
        int r = ch >> 4;                 // 0..63
        int c4 = (ch & 15) * 4;
        float4 v = *(const float4*)(src + (size_t)(r0 + r) * 1024 + c0 + c4);
        tbuf[r][c4] = v.x; tbuf[r][c4+1] = v.y; tbuf[r][c4+2] = v.z; tbuf[r][c4+3] = v.w;
    }
    __syncthreads();
    int c = tid >> 2;                    // 0..63  (source col = dest row)
    int rseg = (tid & 3) * 16;
    us8 o0, o1;
    #pragma unroll
    for (int j = 0; j < 8; ++j) o0[j] = f2bf(tbuf[rseg + j][c]);
    #pragma unroll
    for (int j = 0; j < 8; ++j) o1[j] = f2bf(tbuf[rseg + 8 + j][c]);
    *(us8*)(dst + (size_t)(c0 + c) * 1024 + r0 + rseg) = o0;
    *(us8*)(dst + (size_t)(c0 + c) * 1024 + r0 + rseg + 8) = o1;
}

// ---------------- MFMA GEMM core: C[m][n] = sum_k A[m][k]*B[n][k] ----------------
// 128x128 tile, BK=32, 4 waves (2x2), 16x16x32 bf16 MFMA, global_load_lds staging.
__device__ __forceinline__ void gemm_easy(const u16* __restrict__ A, int lda,
                                          const u16* __restrict__ B0, const u16* __restrict__ B1,
                                          int ldb, int ksplit, int K, f32x4 (&acc)[4][4]) {
    __shared__ u16 sA[128 * 32];
    __shared__ u16 sB[128 * 32];
    const int tid = threadIdx.x;
    const int lane = tid & 63;
    const int wv = tid >> 6;
    const int wr = (wv >> 1) * 64, wc = (wv & 1) * 64;
    const int l15 = lane & 15, lk = (lane >> 4) * 8;
    const int m0 = blockIdx.y * 128, n0 = blockIdx.x * 128;
    const int r0 = tid >> 2;             // staging row 0..63
    const int k8 = (tid & 3) * 8;        // staging k offset

    for (int k0 = 0; k0 < K; k0 += 32) {
        const u16* Bp; int kb;
        if (k0 < ksplit) { Bp = B0; kb = k0; } else { Bp = B1; kb = k0 - ksplit; }
        gld16(A  + (size_t)(m0 + r0) * lda + k0 + k8,      &sA[tid * 8]);
        gld16(A  + (size_t)(m0 + 64 + r0) * lda + k0 + k8, &sA[2048 + tid * 8]);
        gld16(Bp + (size_t)(n0 + r0) * ldb + kb + k8,      &sB[tid * 8]);
        gld16(Bp + (size_t)(n0 + 64 + r0) * ldb + kb + k8, &sB[2048 + tid * 8]);
        __syncthreads();
        bffrag av[4], bv[4];
        #pragma unroll
        for (int m = 0; m < 4; ++m)
            av[m] = *reinterpret_cast<const bffrag*>(&sA[(wr + m * 16 + l15) * 32 + lk]);
        #pragma unroll
        for (int n = 0; n < 4; ++n)
            bv[n] = *reinterpret_cast<const bffrag*>(&sB[(wc + n * 16 + l15) * 32 + lk]);
        #pragma unroll
        for (int m = 0; m < 4; ++m)
            #pragma unroll
            for (int n = 0; n < 4; ++n)
                acc[m][n] = __builtin_amdgcn_mfma_f32_16x16x32_bf16(av[m], bv[n], acc[m][n], 0, 0, 0);
        __syncthreads();
    }
}

__device__ __forceinline__ void zero_acc(f32x4 (&acc)[4][4]) {
    #pragma unroll
    for (int m = 0; m < 4; ++m)
        #pragma unroll
        for (int n = 0; n < 4; ++n)
            #pragma unroll
            for (int i = 0; i < 4; ++i) acc[m][n][i] = 0.f;
}

// D layout: col = lane&15 (+n*16), row = (lane>>4)*4 + i (+m*16)  [m89/m91 verified]
__device__ __forceinline__ void epilogue_bf16(u16* __restrict__ C, int ldc, int coloff,
                                              const f32x4 (&acc)[4][4],
                                              const float* __restrict__ biasN,
                                              const float* __restrict__ biasM) {
    const int tid = threadIdx.x, lane = tid & 63, wv = tid >> 6;
    const int wr = (wv >> 1) * 64, wc = (wv & 1) * 64;
    const int m0 = blockIdx.y * 128, n0 = blockIdx.x * 128;
    const int l15 = lane & 15, l4 = (lane >> 4) * 4;
    #pragma unroll
    for (int m = 0; m < 4; ++m) {
        #pragma unroll
        for (int n = 0; n < 4; ++n) {
            int col = n0 + wc + n * 16 + l15;
            float bn = biasN ? biasN[col] : 0.f;
            #pragma unroll
            for (int i = 0; i < 4; ++i) {
                int row = m0 + wr + m * 16 + l4 + i;
                float v = acc[m][n][i] + bn + (biasM ? biasM[row] : 0.f);
                C[(size_t)row * ldc + coloff + col] = f2bf(v);
            }
        }
    }
}

__device__ __forceinline__ void epilogue_f32(float* __restrict__ C, int ldc, float scale,
                                             const f32x4 (&acc)[4][4],
                                             const float* __restrict__ bias1,
                                             const float* __restrict__ bias2) {
    const int tid = threadIdx.x, lane = tid & 63, wv = tid >> 6;
    const int wr = (wv >> 1) * 64, wc = (wv & 1) * 64;
    const int m0 = blockIdx.y * 128, n0 = blockIdx.x * 128;
    const int l15 = lane & 15, l4 = (lane >> 4) * 4;
    #pragma unroll
    for (int m = 0; m < 4; ++m) {
        #pragma unroll
        for (int n = 0; n < 4; ++n) {
            int col = n0 + wc + n * 16 + l15;
            float bn = (bias1 ? bias1[col] : 0.f) + (bias2 ? bias2[col] : 0.f);
            #pragma unroll
            for (int i = 0; i < 4; ++i) {
                int row = m0 + wr + m * 16 + l4 + i;
                C[(size_t)row * ldc + col] = acc[m][n][i] * scale + bn;
            }
        }
    }
}

// ---------------- GEMM wrapper kernels ----------------
// z: 0..15  w=z>>3 (0=Q,1=K), bs=z&7 (b*2+slot)
__global__ __launch_bounds__(256) void mfma_qk(const u16* __restrict__ Xb,
        const u16* __restrict__ WqT, const u16* __restrict__ WkT,
        const float* __restrict__ bq, const float* __restrict__ bk,
        const int* __restrict__ sel, u16* __restrict__ Qb, u16* __restrict__ Kb) {
    int z = blockIdx.z, w = z >> 3, bs = z & 7;
    int b = bs >> 1, e = sel[bs];
    const u16* A = Xb + ((size_t)b << 20);
    const u16* B = (w ? WkT : WqT) + ((size_t)e << 20);
    const float* bias = (w ? bk : bq) + e * 1024;
    u16* C = (w ? Kb : Qb) + ((size_t)bs << 20);
    f32x4 acc[4][4]; zero_acc(acc);
    gemm_easy(A, 1024, B, B, 1024, 1 << 30, 1024, acc);
    epilogue_bf16(C, 1024, 0, acc, bias, nullptr);
}

// Vt[h][t] = sum_d WvT[h][d] * X[t][d]  (V computed pre-transposed; bias along rows h)
__global__ __launch_bounds__(256) void mfma_v(const u16* __restrict__ Xb,
        const u16* __restrict__ WvT, const float* __restrict__ bv,
        const int* __restrict__ sel, u16* __restrict__ Vt) {
    int bs = blockIdx.z, b = bs >> 1, e = sel[bs];
    const u16* A = WvT + ((size_t)e << 20);
    const u16* B = Xb + ((size_t)b << 20);
    f32x4 acc[4][4]; zero_acc(acc);
    gemm_easy(A, 1024, B, B, 1024, 1 << 30, 1024, acc);
    epilogue_bf16(Vt + ((size_t)bs << 20), 1024, 0, acc, nullptr, bv + e * 1024);
}

__global__ __launch_bounds__(256) void mfma_scores(const u16* __restrict__ Qb,
        const u16* __restrict__ Kb, float* __restrict__ S) {
    int bs = blockIdx.z;
    const u16* A = Qb + ((size_t)bs << 20);
    const u16* B = Kb + ((size_t)bs << 20);
    f32x4 acc[4][4]; zero_acc(acc);
    gemm_easy(A, 1024, B, B, 1024, 1 << 30, 1024, acc);
    epilogue_f32(S + ((size_t)bs << 20), 1024, SCALE_QK, acc, nullptr, nullptr);
}

// A[b][s][t] = softmax(S[b,0]) + softmax(S[b,1])  -> bf16
__global__ __launch_bounds__(256) void sm_combine(const float* __restrict__ S, u16* __restrict__ Ab) {
    __shared__ float red[256];
    int bs = blockIdx.x, b = bs >> 10, s = bs & 1023;
    const float* S0 = S + ((size_t)(b * 2) << 20) + (size_t)s * 1024;
    const float* S1 = S0 + (1u << 20);
    int t = threadIdx.x;
    float4 x0 = *(const float4*)(S0 + t * 4);
    float4 x1 = *(const float4*)(S1 + t * 4);
    float m0 = fmaxf(fmaxf(x0.x, x0.y), fmaxf(x0.z, x0.w));
    float m1 = fmaxf(fmaxf(x1.x, x1.y), fmaxf(x1.z, x1.w));
    red[t] = m0; __syncthreads();
    for (int off = 128; off; off >>= 1) { if (t < off) red[t] = fmaxf(red[t], red[t+off]); __syncthreads(); }
    m0 = red[0]; __syncthreads();
    red[t] = m1; __syncthreads();
    for (int off = 128; off; off >>= 1) { if (t < off) red[t] = fmaxf(red[t], red[t+off]); __syncthreads(); }
    m1 = red[0]; __syncthreads();
    float4 e0, e1;
    e0.x = __expf(x0.x - m0); e0.y = __expf(x0.y - m0); e0.z = __expf(x0.z - m0); e0.w = __expf(x0.w - m0);
    e1.x = __expf(x1.x - m1); e1.y = __expf(x1.y - m1); e1.z = __expf(x1.z - m1); e1.w = __expf(x1.w - m1);
    red[t] = e0.x + e0.y + e0.z + e0.w; __syncthreads();
    for (int off = 128; off; off >>= 1) { if (t < off) red[t] += red[t+off]; __syncthreads(); }
    float s0 = red[0]; __syncthreads();
    red[t] = e1.x + e1.y + e1.z + e1.w; __syncthreads();
    for (int off = 128; off; off >>= 1) { if (t < off) red[t] += red[t+off]; __syncthreads(); }
    float s1 = red[0];
    float r0 = 1.f / s0, r1 = 1.f / s1;
    us4 o;
    o[0] = f2bf(e0.x * r0 + e1.x * r1); o[1] = f2bf(e0.y * r0 + e1.y * r1);
    o[2] = f2bf(e0.z * r0 + e1.z * r1); o[3] = f2bf(e0.w * r0 + e1.w * r1);
    *(us4*)(Ab + ((size_t)b << 20) + (size_t)s * 1024 + t * 4) = o;
}

// ctxcat[b][s][slot*1024 + h] = sum_t A[b][s][t] * Vt[bs][h][t]
__global__ __launch_bounds__(256) void mfma_ctx(const u16* __restrict__ Ab,
        const u16* __restrict__ Vt, u16* __restrict__ ctx) {
    int bs = blockIdx.z, b = bs >> 1, slot = bs & 1;
    const u16* A = Ab + ((size_t)b << 20);
    const u16* B = Vt + ((size_t)bs << 20);
    f32x4 acc[4][4]; zero_acc(acc);
    gemm_easy(A, 1024, B, B, 1024, 1 << 30, 1024, acc);
    epilogue_bf16(ctx + ((size_t)b << 21), 2048, slot * 1024, acc, nullptr, nullptr);
}

// y[b][s][d] = sum_{k<2048} ctxcat[b][s][k] * Wcat[d][k] + bff[e0][d] + bff[e1][d]
__global__ __launch_bounds__(256) void mfma_out(const u16* __restrict__ ctx,
        const u16* __restrict__ WffT, const float* __restrict__ bff,
        const int* __restrict__ sel, float* __restrict__ y) {
    int b = blockIdx.z;
    int e0 = sel[b * 2], e1 = sel[b * 2 + 1];
    const u16* A = ctx + ((size_t)b << 21);
    const u16* B0 = WffT + ((size_t)e0 << 20);
    const u16* B1 = WffT + ((size_t)e1 << 20);
    f32x4 acc[4][4]; zero_acc(acc);
    gemm_easy(A, 2048, B0, B1, 1024, 1024, 2048, acc);
    epilogue_f32(y + ((size_t)b << 20), 1024, 1.0f, acc, bff + e0 * 1024, bff + e1 * 1024);
}

// ---------------- launcher ----------------
extern "C" void kernel_launch(void* const* d_in, const int* in_sizes, int n_in,
                              void* d_out, int out_size, void* d_ws, size_t ws_size,
                              hipStream_t stream) {
    const float* X   = (const float*)d_in[0];
    const float* sW  = (const float*)d_in[2];
    const float* sb  = (const float*)d_in[3];
    const float* Wq  = (const float*)d_in[4];
    const float* bq  = (const float*)d_in[5];
    const float* Wk  = (const float*)d_in[6];
    const float* bk  = (const float*)d_in[7];
    const float* Wv  = (const float*)d_in[8];
    const float* bv  = (const float*)d_in[9];
    const float* Wff = (const float*)d_in[10];
    const float* bff = (const float*)d_in[11];
    float* y = (float*)d_out;

    char* w = (char*)d_ws;
    float* part = (float*)w;                       // 32 KB
    int*   sel  = (int*)(w + 32768);               // 8 ints
    u16* Xb   = (u16*)(w + 65536);                 // 4M u16 = 8 MB
    u16* WqT  = Xb   + (4u << 20);                 // each 8M u16 = 16 MB
    u16* WkT  = WqT  + (8u << 20);
    u16* WvT  = WkT  + (8u << 20);
    u16* WffT = WvT  + (8u << 20);
    u16* Qb   = WffT + (8u << 20);
    u16* Kb   = Qb   + (8u << 20);
    u16* Vt   = Kb   + (8u << 20);
    u16* Abf  = Vt   + (8u << 20);                 // 4M u16
    u16* ctx  = Abf  + (4u << 20);                 // 8M u16 (4 x [1024][2048])
    float* S  = (float*)(ctx + (8u << 20));        // 8M f32 = 32 MB
    // total ws use ~176 MB

    router_partial<<<256, 256, 0, stream>>>(X, sW, part);
    router_final<<<1, 256, 0, stream>>>(part, sb, sel);
    cvt_x<<<2048, 256, 0, stream>>>(X, Xb);
    cvt_w_t<<<dim3(16, 16, 32), 256, 0, stream>>>(Wq, Wk, Wv, Wff, WqT, WkT, WvT, WffT);

    mfma_qk<<<dim3(8, 8, 16), 256, 0, stream>>>(Xb, WqT, WkT, bq, bk, sel, Qb, Kb);
    mfma_v<<<dim3(8, 8, 8), 256, 0, stream>>>(Xb, WvT, bv, sel, Vt);
    mfma_scores<<<dim3(8, 8, 8), 256, 0, stream>>>(Qb, Kb, S);
    sm_combine<<<4096, 256, 0, stream>>>(S, Abf);
    mfma_ctx<<<dim3(8, 8, 8), 256, 0, stream>>>(Abf, Vt, ctx);
    mfma_out<<<dim3(8, 8, 4), 256, 0, stream>>>(ctx, WffT, bff, sel, y);
}

// Round 3
// 272.966 us; speedup vs baseline: 5.6425x; 1.0725x over previous
//
#include <hip/hip_runtime.h>
#include <math.h>

typedef unsigned short u16;
typedef __attribute__((ext_vector_type(8))) short bffrag;   // 8 bf16 MFMA operand
typedef __attribute__((ext_vector_type(4))) float f32x4;    // MFMA accumulator
typedef __attribute__((ext_vector_type(4))) unsigned short us4;
typedef __attribute__((ext_vector_type(8))) unsigned short us8;

#define SCALE_QK (1.0f/32.0f)

// fp32 -> bf16 round-to-nearest-even (bit trick, NaN-free inputs)
__device__ __forceinline__ u16 f2bf(float f) {
    unsigned u = __builtin_bit_cast(unsigned, f);
    u += 0x7fffu + ((u >> 16) & 1u);
    return (u16)(u >> 16);
}

__device__ __forceinline__ void gld16(const u16* g, u16* l) {
    __builtin_amdgcn_global_load_lds(
        (const __attribute__((address_space(1))) void*)g,
        (__attribute__((address_space(3))) void*)l, 16, 0, 0);
}

// ---------------- router (fp32, exact) ----------------
__global__ __launch_bounds__(256) void router_partial(const float* __restrict__ X,
                                                      const float* __restrict__ sW,
                                                      float* __restrict__ part) {
    float acc[32];
    #pragma unroll
    for (int a = 0; a < 32; ++a) acc[a] = 0.f;
    int tid = blockIdx.x * 256 + threadIdx.x;
    #pragma unroll
    for (int q = 0; q < 4; ++q) {
        int i = tid + q * 262144;
        float4 w0 = *(const float4*)(sW + (size_t)i * 8);
        float4 w1 = *(const float4*)(sW + (size_t)i * 8 + 4);
        #pragma unroll
        for (int b = 0; b < 4; ++b) {
            float x = X[((size_t)b << 20) + i];
            acc[b*8+0] += x * w0.x; acc[b*8+1] += x * w0.y;
            acc[b*8+2] += x * w0.z; acc[b*8+3] += x * w0.w;
            acc[b*8+4] += x * w1.x; acc[b*8+5] += x * w1.y;
            acc[b*8+6] += x * w1.z; acc[b*8+7] += x * w1.w;
        }
    }
    __shared__ float wsum[4][32];
    int lane = threadIdx.x & 63, wv = threadIdx.x >> 6;
    #pragma unroll
    for (int a = 0; a < 32; ++a) {
        float v = acc[a];
        #pragma unroll
        for (int off = 32; off; off >>= 1) v += __shfl_down(v, off, 64);
        if (lane == 0) wsum[wv][a] = v;
    }
    __syncthreads();
    int t = threadIdx.x;
    if (t < 32)
        part[(size_t)t * 1024 + blockIdx.x] = wsum[0][t] + wsum[1][t] + wsum[2][t] + wsum[3][t];
}

// reduce partials, add bias, top-2 per batch (ties -> lowest index), publish need flags
__global__ __launch_bounds__(256) void router_final(const float* __restrict__ part,
                                                    const float* __restrict__ sb,
                                                    int* __restrict__ sel_need) {
    __shared__ float ps[32][8];
    __shared__ float lg[32];
    int t = threadIdx.x, a = t >> 3, c = t & 7;
    {
        float s = 0.f;
        const float* p = part + (size_t)a * 1024 + c * 128;
        for (int i = 0; i < 128; ++i) s += p[i];
        ps[a][c] = s;
    }
    __syncthreads();
    if (t < 32) {
        float v = 0.f;
        #pragma unroll
        for (int j = 0; j < 8; ++j) v += ps[t][j];
        lg[t] = v + sb[t & 7];
    }
    __syncthreads();
    if (t < 4) {
        int base = t * 8;
        int e1 = 0; float v1 = lg[base];
        for (int e = 1; e < 8; ++e) { if (lg[base + e] > v1) { v1 = lg[base + e]; e1 = e; } }
        int e2 = -1; float v2 = -INFINITY;
        for (int e = 0; e < 8; ++e) {
            if (e == e1) continue;
            if (lg[base + e] > v2) { v2 = lg[base + e]; e2 = e; }
        }
        sel_need[t * 2] = e1; sel_need[t * 2 + 1] = e2;
    }
    __syncthreads();
    if (t < 8) {
        int need = 0;
        for (int j = 0; j < 8; ++j) need |= (sel_need[j] == t);
        sel_need[8 + t] = need;
    }
}

// ---------------- converts ----------------
__global__ __launch_bounds__(256) void cvt_x(const float* __restrict__ X, u16* __restrict__ Xb) {
    int i = (blockIdx.x * 256 + threadIdx.x) * 8;
    float4 a = *(const float4*)(X + i);
    float4 b = *(const float4*)(X + i + 4);
    us8 o;
    o[0] = f2bf(a.x); o[1] = f2bf(a.y); o[2] = f2bf(a.z); o[3] = f2bf(a.w);
    o[4] = f2bf(b.x); o[5] = f2bf(b.y); o[6] = f2bf(b.z); o[7] = f2bf(b.w);
    *(us8*)(Xb + i) = o;
}

// transpose + convert selected experts' weight matrices -> bf16 transposed
__global__ __launch_bounds__(256) void cvt_w_t(const float* __restrict__ Wq,
                                               const float* __restrict__ Wk,
                                               const float* __restrict__ Wv,
                                               const float* __restrict__ Wff,
                                               const int* __restrict__ sel_need,
                                               u16* __restrict__ WqT, u16* __restrict__ WkT,
                                               u16* __restrict__ WvT, u16* __restrict__ WffT) {
    int z = blockIdx.z;                  // 0..31
    int which = z >> 3, e = z & 7;
    if (!sel_need[8 + e]) return;        // expert not routed anywhere
    __shared__ float tbuf[64][65];
    const float* src = (which == 0 ? Wq : which == 1 ? Wk : which == 2 ? Wv : Wff) + ((size_t)e << 20);
    u16* dst = (which == 0 ? WqT : which == 1 ? WkT : which == 2 ? WvT : WffT) + ((size_t)e << 20);
    int r0 = blockIdx.y * 64, c0 = blockIdx.x * 64;
    int tid = threadIdx.x;
    #pragma unroll
    for (int q = 0; q < 4; ++q) {
        int ch = q * 256 + tid;          // 0..1023
        int r = ch >> 4;                 // 0..63
        int c4 = (ch & 15) * 4;
        float4 v = *(const float4*)(src + (size_t)(r0 + r) * 1024 + c0 + c4);
        tbuf[r][c4] = v.x; tbuf[r][c4+1] = v.y; tbuf[r][c4+2] = v.z; tbuf[r][c4+3] = v.w;
    }
    __syncthreads();
    int c = tid >> 2;                    // 0..63  (source col = dest row)
    int rseg = (tid & 3) * 16;
    us8 o0, o1;
    #pragma unroll
    for (int j = 0; j < 8; ++j) o0[j] = f2bf(tbuf[rseg + j][c]);
    #pragma unroll
    for (int j = 0; j < 8; ++j) o1[j] = f2bf(tbuf[rseg + 8 + j][c]);
    *(us8*)(dst + (size_t)(c0 + c) * 1024 + r0 + rseg) = o0;
    *(us8*)(dst + (size_t)(c0 + c) * 1024 + r0 + rseg + 8) = o1;
}

// ---------------- MFMA GEMM core: C[m][n] = sum_k A[m][k]*B[n][k] ----------------
// 128x128 tile, BK=32, 4 waves (2x2), 16x16x32 bf16 MFMA.
// Double-buffered: STAGE(t+1) issued before ds_read/MFMA of tile t; single barrier
// per K-step drains vmcnt (prefetch) + protects LDS reuse (T3-minimum 2-phase).
__device__ __forceinline__ void stage_tile(const u16* a0, const u16* a1,
                                           const u16* b0, const u16* b1,
                                           u16* sa, u16* sb, int tid) {
    gld16(a0, &sa[tid * 8]);
    gld16(a1, &sa[2048 + tid * 8]);
    gld16(b0, &sb[tid * 8]);
    gld16(b1, &sb[2048 + tid * 8]);
}

__device__ __forceinline__ void gemm_db(const u16* __restrict__ A, int lda,
                                        const u16* __restrict__ B0, const u16* __restrict__ B1,
                                        int ldb, int ksplit, int K, f32x4 (&acc)[4][4]) {
    __shared__ u16 sA[2][4096];
    __shared__ u16 sB[2][4096];
    const int tid = threadIdx.x, lane = tid & 63, wv = tid >> 6;
    const int wr = (wv >> 1) * 64, wc = (wv & 1) * 64;
    const int l15 = lane & 15, lk = (lane >> 4) * 8;
    const int m0 = blockIdx.y * 128, n0 = blockIdx.x * 128;
    const int r0 = tid >> 2, k8 = (tid & 3) * 8;

    const u16* a0 = A + (size_t)(m0 + r0) * lda + k8;
    const u16* a1 = A + (size_t)(m0 + 64 + r0) * lda + k8;

    // prologue: stage tile 0
    {
        const u16* Bp = B0;
        stage_tile(a0, a1,
                   Bp + (size_t)(n0 + r0) * ldb + k8,
                   Bp + (size_t)(n0 + 64 + r0) * ldb + k8,
                   sA[0], sB[0], tid);
    }
    __syncthreads();

    const int nt = K >> 5;
    for (int t = 0; t < nt; ++t) {
        const int cur = t & 1;
        if (t + 1 < nt) {
            int k0 = (t + 1) << 5;
            const u16* Bp; int kb;
            if (k0 < ksplit) { Bp = B0; kb = k0; } else { Bp = B1; kb = k0 - ksplit; }
            stage_tile(a0 + k0, a1 + k0,
                       Bp + (size_t)(n0 + r0) * ldb + kb + k8,
                       Bp + (size_t)(n0 + 64 + r0) * ldb + kb + k8,
                       sA[cur ^ 1], sB[cur ^ 1], tid);
        }
        bffrag av[4], bf[4];
        #pragma unroll
        for (int m = 0; m < 4; ++m)
            av[m] = *reinterpret_cast<const bffrag*>(&sA[cur][(wr + m * 16 + l15) * 32 + lk]);
        #pragma unroll
        for (int n = 0; n < 4; ++n)
            bf[n] = *reinterpret_cast<const bffrag*>(&sB[cur][(wc + n * 16 + l15) * 32 + lk]);
        #pragma unroll
        for (int m = 0; m < 4; ++m)
            #pragma unroll
            for (int n = 0; n < 4; ++n)
                acc[m][n] = __builtin_amdgcn_mfma_f32_16x16x32_bf16(av[m], bf[n], acc[m][n], 0, 0, 0);
        __syncthreads();   // drains prefetch vmcnt + protects buf reuse
    }
}

__device__ __forceinline__ void zero_acc(f32x4 (&acc)[4][4]) {
    #pragma unroll
    for (int m = 0; m < 4; ++m)
        #pragma unroll
        for (int n = 0; n < 4; ++n)
            #pragma unroll
            for (int i = 0; i < 4; ++i) acc[m][n][i] = 0.f;
}

// D layout: col = lane&15 (+n*16), row = (lane>>4)*4 + i (+m*16)  [m89/m91 verified]
__device__ __forceinline__ void epilogue_bf16(u16* __restrict__ C, int ldc, int coloff,
                                              const f32x4 (&acc)[4][4],
                                              const float* __restrict__ biasN,
                                              const float* __restrict__ biasM) {
    const int tid = threadIdx.x, lane = tid & 63, wv = tid >> 6;
    const int wr = (wv >> 1) * 64, wc = (wv & 1) * 64;
    const int m0 = blockIdx.y * 128, n0 = blockIdx.x * 128;
    const int l15 = lane & 15, l4 = (lane >> 4) * 4;
    #pragma unroll
    for (int m = 0; m < 4; ++m) {
        #pragma unroll
        for (int n = 0; n < 4; ++n) {
            int col = n0 + wc + n * 16 + l15;
            float bn = biasN ? biasN[col] : 0.f;
            #pragma unroll
            for (int i = 0; i < 4; ++i) {
                int row = m0 + wr + m * 16 + l4 + i;
                float v = acc[m][n][i] + bn + (biasM ? biasM[row] : 0.f);
                C[(size_t)row * ldc + coloff + col] = f2bf(v);
            }
        }
    }
}

__device__ __forceinline__ void epilogue_f32(float* __restrict__ C, int ldc, float scale,
                                             const f32x4 (&acc)[4][4],
                                             const float* __restrict__ bias1,
                                             const float* __restrict__ bias2) {
    const int tid = threadIdx.x, lane = tid & 63, wv = tid >> 6;
    const int wr = (wv >> 1) * 64, wc = (wv & 1) * 64;
    const int m0 = blockIdx.y * 128, n0 = blockIdx.x * 128;
    const int l15 = lane & 15, l4 = (lane >> 4) * 4;
    #pragma unroll
    for (int m = 0; m < 4; ++m) {
        #pragma unroll
        for (int n = 0; n < 4; ++n) {
            int col = n0 + wc + n * 16 + l15;
            float bn = (bias1 ? bias1[col] : 0.f) + (bias2 ? bias2[col] : 0.f);
            #pragma unroll
            for (int i = 0; i < 4; ++i) {
                int row = m0 + wr + m * 16 + l4 + i;
                C[(size_t)row * ldc + col] = acc[m][n][i] * scale + bn;
            }
        }
    }
}

// ---------------- GEMM wrapper kernels ----------------
// z: 0..23  w=z>>3 (0=Q,1=K,2=V), bs=z&7 (b*2+slot)
__global__ __launch_bounds__(256) void mfma_qkv(const u16* __restrict__ Xb,
        const u16* __restrict__ WqT, const u16* __restrict__ WkT, const u16* __restrict__ WvT,
        const float* __restrict__ bq, const float* __restrict__ bk, const float* __restrict__ bv,
        const int* __restrict__ sel, u16* __restrict__ Qb, u16* __restrict__ Kb,
        u16* __restrict__ Vt) {
    int z = blockIdx.z, w = z >> 3, bs = z & 7;
    int b = bs >> 1, e = sel[bs];
    f32x4 acc[4][4]; zero_acc(acc);
    if (w < 2) {
        const u16* A = Xb + ((size_t)b << 20);
        const u16* B = (w ? WkT : WqT) + ((size_t)e << 20);
        gemm_db(A, 1024, B, B, 1024, 1024, 1024, acc);
        epilogue_bf16((w ? Kb : Qb) + ((size_t)bs << 20), 1024, 0, acc,
                      (w ? bk : bq) + e * 1024, nullptr);
    } else {
        // Vt[h][t] = sum_d WvT[h][d] * X[t][d]  (V pre-transposed; bias along rows h)
        gemm_db(WvT + ((size_t)e << 20), 1024, Xb + ((size_t)b << 20),
                Xb + ((size_t)b << 20), 1024, 1024, 1024, acc);
        epilogue_bf16(Vt + ((size_t)bs << 20), 1024, 0, acc, nullptr, bv + e * 1024);
    }
}

__global__ __launch_bounds__(256) void mfma_scores(const u16* __restrict__ Qb,
        const u16* __restrict__ Kb, float* __restrict__ S) {
    int bs = blockIdx.z;
    const u16* A = Qb + ((size_t)bs << 20);
    const u16* B = Kb + ((size_t)bs << 20);
    f32x4 acc[4][4]; zero_acc(acc);
    gemm_db(A, 1024, B, B, 1024, 1024, 1024, acc);
    epilogue_f32(S + ((size_t)bs << 20), 1024, SCALE_QK, acc, nullptr, nullptr);
}

// A[b][s][t] = softmax(S[b,0]) + softmax(S[b,1])  -> bf16
__global__ __launch_bounds__(256) void sm_combine(const float* __restrict__ S, u16* __restrict__ Ab) {
    int bs = blockIdx.x, b = bs >> 10, s = bs & 1023;
    const float* S0 = S + ((size_t)(b * 2) << 20) + (size_t)s * 1024;
    const float* S1 = S0 + (1u << 20);
    int t = threadIdx.x, lane = t & 63, wv = t >> 6;
    float4 x0 = *(const float4*)(S0 + t * 4);
    float4 x1 = *(const float4*)(S1 + t * 4);
    float m0 = fmaxf(fmaxf(x0.x, x0.y), fmaxf(x0.z, x0.w));
    float m1 = fmaxf(fmaxf(x1.x, x1.y), fmaxf(x1.z, x1.w));
    #pragma unroll
    for (int off = 32; off; off >>= 1) {
        m0 = fmaxf(m0, __shfl_xor(m0, off, 64));
        m1 = fmaxf(m1, __shfl_xor(m1, off, 64));
    }
    __shared__ float wred[4][4];
    if (lane == 0) { wred[wv][0] = m0; wred[wv][1] = m1; }
    __syncthreads();
    m0 = fmaxf(fmaxf(wred[0][0], wred[1][0]), fmaxf(wred[2][0], wred[3][0]));
    m1 = fmaxf(fmaxf(wred[0][1], wred[1][1]), fmaxf(wred[2][1], wred[3][1]));
    float4 e0, e1;
    e0.x = __expf(x0.x - m0); e0.y = __expf(x0.y - m0); e0.z = __expf(x0.z - m0); e0.w = __expf(x0.w - m0);
    e1.x = __expf(x1.x - m1); e1.y = __expf(x1.y - m1); e1.z = __expf(x1.z - m1); e1.w = __expf(x1.w - m1);
    float s0 = e0.x + e0.y + e0.z + e0.w;
    float s1 = e1.x + e1.y + e1.z + e1.w;
    #pragma unroll
    for (int off = 32; off; off >>= 1) {
        s0 += __shfl_xor(s0, off, 64);
        s1 += __shfl_xor(s1, off, 64);
    }
    if (lane == 0) { wred[wv][2] = s0; wred[wv][3] = s1; }
    __syncthreads();
    s0 = wred[0][2] + wred[1][2] + wred[2][2] + wred[3][2];
    s1 = wred[0][3] + wred[1][3] + wred[2][3] + wred[3][3];
    float r0 = 1.f / s0, r1 = 1.f / s1;
    us4 o;
    o[0] = f2bf(e0.x * r0 + e1.x * r1); o[1] = f2bf(e0.y * r0 + e1.y * r1);
    o[2] = f2bf(e0.z * r0 + e1.z * r1); o[3] = f2bf(e0.w * r0 + e1.w * r1);
    *(us4*)(Ab + ((size_t)b << 20) + (size_t)s * 1024 + t * 4) = o;
}

// ctxcat[b][s][slot*1024 + h] = sum_t A[b][s][t] * Vt[bs][h][t]
__global__ __launch_bounds__(256) void mfma_ctx(const u16* __restrict__ Ab,
        const u16* __restrict__ Vt, u16* __restrict__ ctx) {
    int bs = blockIdx.z, b = bs >> 1, slot = bs & 1;
    const u16* A = Ab + ((size_t)b << 20);
    const u16* B = Vt + ((size_t)bs << 20);
    f32x4 acc[4][4]; zero_acc(acc);
    gemm_db(A, 1024, B, B, 1024, 1024, 1024, acc);
    epilogue_bf16(ctx + ((size_t)b << 21), 2048, slot * 1024, acc, nullptr, nullptr);
}

// y[b][s][d] = sum_{k<2048} ctxcat[b][s][k] * Wcat[d][k] + bff[e0][d] + bff[e1][d]
__global__ __launch_bounds__(256) void mfma_out(const u16* __restrict__ ctx,
        const u16* __restrict__ WffT, const float* __restrict__ bff,
        const int* __restrict__ sel, float* __restrict__ y) {
    int b = blockIdx.z;
    int e0 = sel[b * 2], e1 = sel[b * 2 + 1];
    const u16* A = ctx + ((size_t)b << 21);
    const u16* B0 = WffT + ((size_t)e0 << 20);
    const u16* B1 = WffT + ((size_t)e1 << 20);
    f32x4 acc[4][4]; zero_acc(acc);
    gemm_db(A, 2048, B0, B1, 1024, 1024, 2048, acc);
    epilogue_f32(y + ((size_t)b << 20), 1024, 1.0f, acc, bff + e0 * 1024, bff + e1 * 1024);
}

// ---------------- launcher ----------------
extern "C" void kernel_launch(void* const* d_in, const int* in_sizes, int n_in,
                              void* d_out, int out_size, void* d_ws, size_t ws_size,
                              hipStream_t stream) {
    const float* X   = (const float*)d_in[0];
    const float* sW  = (const float*)d_in[2];
    const float* sb  = (const float*)d_in[3];
    const float* Wq  = (const float*)d_in[4];
    const float* bq  = (const float*)d_in[5];
    const float* Wk  = (const float*)d_in[6];
    const float* bk  = (const float*)d_in[7];
    const float* Wv  = (const float*)d_in[8];
    const float* bv  = (const float*)d_in[9];
    const float* Wff = (const float*)d_in[10];
    const float* bff = (const float*)d_in[11];
    float* y = (float*)d_out;

    char* w = (char*)d_ws;
    float* part = (float*)w;                       // 1024*32 floats = 128 KB
    int*   sel  = (int*)(w + (1u << 17));          // sel[0..7] + need[8..15]
    u16* Xb   = (u16*)(w + (1u << 18));            // 4M u16 = 8 MB
    u16* WqT  = Xb   + (4u << 20);                 // each 8M u16 = 16 MB
    u16* WkT  = WqT  + (8u << 20);
    u16* WvT  = WkT  + (8u << 20);
    u16* WffT = WvT  + (8u << 20);
    u16* Qb   = WffT + (8u << 20);
    u16* Kb   = Qb   + (8u << 20);
    u16* Vt   = Kb   + (8u << 20);
    u16* Abf  = Vt   + (8u << 20);                 // 4M u16
    u16* ctx  = Abf  + (4u << 20);                 // 8M u16 (4 x [1024][2048])
    float* S  = (float*)(ctx + (8u << 20));        // 8M f32 = 32 MB

    router_partial<<<1024, 256, 0, stream>>>(X, sW, part);
    router_final<<<1, 256, 0, stream>>>(part, sb, sel);
    cvt_x<<<2048, 256, 0, stream>>>(X, Xb);
    cvt_w_t<<<dim3(16, 16, 32), 256, 0, stream>>>(Wq, Wk, Wv, Wff, sel, WqT, WkT, WvT, WffT);

    mfma_qkv<<<dim3(8, 8, 24), 256, 0, stream>>>(Xb, WqT, WkT, WvT, bq, bk, bv, sel, Qb, Kb, Vt);
    mfma_scores<<<dim3(8, 8, 8), 256, 0, stream>>>(Qb, Kb, S);
    sm_combine<<<4096, 256, 0, stream>>>(S, Abf);
    mfma_ctx<<<dim3(8, 8, 8), 256, 0, stream>>>(Abf, Vt, ctx);
    mfma_out<<<dim3(8, 8, 4), 256, 0, stream>>>(ctx, WffT, bff, sel, y);
}